// Round 1
// baseline (204.893 us; speedup 1.0000x reference)
//
#include <hip/hip_runtime.h>

#define H_ 1024
#define W_ 1024
#define B_ 4
#define CIN 16
#define COUT 16
#define TH 8
#define TW 64
#define LDS_COLS 66   // TW+2
#define LDS_ROWS 10   // TH+2
#define PIX_STRIDE 24 // in u16 units -> 48B per pixel (16 ch used + 8 pad)

#define LRELU 0.2f
#define GAIN_ 1.4142135623730951f
#define EPS_ 1e-8f

typedef __attribute__((ext_vector_type(8))) short bf16x8;
typedef __attribute__((ext_vector_type(4))) float f32x4;

static __device__ __forceinline__ unsigned short f32_to_bf16(float f) {
    unsigned int u = __float_as_uint(f);
    unsigned int r = u + 0x7FFF + ((u >> 16) & 1);   // RNE
    return (unsigned short)(r >> 16);
}

// ---------------- setup 1: s[b,i] = w @ (fcw.T * 512^-0.5) + bias; copy w to out ----
__global__ __launch_bounds__(256) void k_setup1(
    const float* __restrict__ w, const float* __restrict__ fcw,
    const float* __restrict__ fcb, float* __restrict__ s_out,
    float* __restrict__ w_copy_out)
{
    __shared__ float part[256];
    const int tid = threadIdx.x;
    const int bi = tid >> 2;   // 0..63 -> (b,i)
    const int q  = tid & 3;
    const int b = bi >> 4, i = bi & 15;
    const float* wr = w + b * 512 + q * 128;
    const float* fr = fcw + i * 512 + q * 128;
    float acc = 0.f;
    #pragma unroll 8
    for (int k = 0; k < 128; ++k) acc += wr[k] * fr[k];
    part[tid] = acc;
    __syncthreads();
    if (tid < 64) {
        float v = part[tid*4] + part[tid*4+1] + part[tid*4+2] + part[tid*4+3];
        s_out[tid] = v * 0.04419417382415922f /* 512^-0.5 */ + fcb[tid & 15];
    }
    for (int e = tid; e < B_ * 512; e += 256) w_copy_out[e] = w[e];
}

// ---------------- setup 2: d[b,o], W_eff -> pre-swizzled bf16 A-fragments ----------
// afrag layout: [b][t=0..4][lane=0..63][j=0..7], A[o=lane&15][k=g*8+j],
// k -> (tap = 2t + (g>>1), i = (g&1)*8 + j); tap 9 zeroed.
__global__ __launch_bounds__(256) void k_setup2(
    const float* __restrict__ s_in, const float* __restrict__ convw,
    unsigned short* __restrict__ afrag)
{
    const int b = blockIdx.x;
    const int tid = threadIdx.x;
    __shared__ float s_sh[16];
    __shared__ float d_sh[16];
    __shared__ float wc_sh[COUT * CIN * 9];
    __shared__ float part[256];

    if (tid < 16) s_sh[tid] = s_in[b * 16 + tid];
    for (int e = tid; e < COUT * CIN * 9; e += 256)
        wc_sh[e] = convw[e] * (1.0f / 12.0f);   // (16*9)^-0.5
    __syncthreads();

    const int o = tid >> 4, i = tid & 15;
    const float si = s_sh[i];
    float acc = 0.f;
    #pragma unroll
    for (int tap = 0; tap < 9; ++tap) {
        float v = wc_sh[(o * 16 + i) * 9 + tap] * si;
        acc += v * v;
    }
    part[tid] = acc;
    __syncthreads();
    if (tid < 16) {
        float sum = EPS_;
        #pragma unroll
        for (int j = 0; j < 16; ++j) sum += part[tid * 16 + j];
        d_sh[tid] = rsqrtf(sum);
    }
    __syncthreads();

    for (int e = tid; e < 5 * 64 * 8; e += 256) {
        int t = e >> 9;
        int lane = (e >> 3) & 63;
        int j = e & 7;
        int oo = lane & 15, g = lane >> 4;
        int ii = (g & 1) * 8 + j;
        int tap = 2 * t + (g >> 1);
        float v = 0.f;
        if (tap < 9) v = wc_sh[(oo * 16 + ii) * 9 + tap] * s_sh[ii] * d_sh[oo];
        afrag[(size_t)b * (5 * 64 * 8) + e] = f32_to_bf16(v);
    }
}

// ---------------- main conv: per-tile implicit GEMM via mfma_f32_16x16x32_bf16 ------
__global__ __launch_bounds__(256) void k_conv(
    const float* __restrict__ x, const float* __restrict__ noise,
    const float* __restrict__ conv_bias, const float* __restrict__ sn_ptr,
    const unsigned short* __restrict__ afrag, float* __restrict__ y)
{
    __shared__ unsigned short tile[LDS_ROWS * LDS_COLS * PIX_STRIDE]; // 31.7 KB

    const int tid = threadIdx.x;
    const int bt = blockIdx.z;
    const int h0 = blockIdx.y * TH;
    const int w0 = blockIdx.x * TW;
    const float sn = sn_ptr[0];

    // ---- stage x tile (f32 -> bf16), LDS layout [row][col][ch] ----
    {
        const float* xb = x + (size_t)bt * CIN * H_ * W_;
        // interior columns 1..64 via float4 (gw = w0 + 4*v4, always in range, aligned)
        for (int ve = tid; ve < CIN * LDS_ROWS * 16; ve += 256) {
            int ch  = ve / (LDS_ROWS * 16);
            int rem = ve % (LDS_ROWS * 16);
            int row = rem >> 4;
            int col = 1 + ((rem & 15) << 2);
            int gh = h0 - 1 + row;
            float4 v = make_float4(0.f, 0.f, 0.f, 0.f);
            if (gh >= 0 && gh < H_)
                v = *reinterpret_cast<const float4*>(
                        xb + ((size_t)ch * H_ + gh) * W_ + (w0 - 1 + col));
            unsigned short* dst = &tile[(row * LDS_COLS + col) * PIX_STRIDE + ch];
            dst[0]              = f32_to_bf16(v.x);
            dst[PIX_STRIDE]     = f32_to_bf16(v.y);
            dst[2 * PIX_STRIDE] = f32_to_bf16(v.z);
            dst[3 * PIX_STRIDE] = f32_to_bf16(v.w);
        }
        // edge columns col=0 and col=65
        for (int e = tid; e < CIN * LDS_ROWS * 2; e += 256) {
            int ch  = e / (LDS_ROWS * 2);
            int rem = e % (LDS_ROWS * 2);
            int row = rem >> 1;
            int col = (rem & 1) * (LDS_COLS - 1);
            int gh = h0 - 1 + row;
            int gw = w0 - 1 + col;
            float v = 0.f;
            if (gh >= 0 && gh < H_ && gw >= 0 && gw < W_)
                v = xb[((size_t)ch * H_ + gh) * W_ + gw];
            tile[(row * LDS_COLS + col) * PIX_STRIDE + ch] = f32_to_bf16(v);
        }
    }

    const int lane  = tid & 63;
    const int wid   = tid >> 6;
    const int p     = lane & 15;
    const int g     = lane >> 4;
    const int ghalf = g >> 1;
    const int chalf = g & 1;

    // preload A-fragments (per-batch effective weights) and bias
    bf16x8 a[5];
    {
        const bf16x8* ap =
            reinterpret_cast<const bf16x8*>(afrag + (size_t)bt * 5 * 64 * 8);
        #pragma unroll
        for (int t = 0; t < 5; ++t) a[t] = ap[t * 64 + lane];
    }
    float bias_j[4];
    #pragma unroll
    for (int j = 0; j < 4; ++j) bias_j[j] = conv_bias[g * 4 + j];

    // per-lane tap offsets for the 5 K-slices
    int lroff[5], lcoff[5];
    #pragma unroll
    for (int t = 0; t < 5; ++t) {
        int tap = 2 * t + ghalf;
        if (tap > 8) tap = 8;        // padded slot; A is zero there
        lroff[t] = tap / 3;
        lcoff[t] = tap % 3;
    }

    __syncthreads();

    float* yb = y + (size_t)bt * COUT * H_ * W_;
    const float* nb = noise + (size_t)bt * H_ * W_;

    #pragma unroll
    for (int rr = 0; rr < 2; ++rr) {
        const int oh = wid * 2 + rr;
        #pragma unroll
        for (int gc = 0; gc < 4; ++gc) {
            const int ow = gc * 16;
            f32x4 acc = {0.f, 0.f, 0.f, 0.f};
            #pragma unroll
            for (int t = 0; t < 5; ++t) {
                const unsigned short* src =
                    &tile[((oh + lroff[t]) * LDS_COLS + (ow + p + lcoff[t])) * PIX_STRIDE
                          + chalf * 8];
                bf16x8 bv = *reinterpret_cast<const bf16x8*>(src);
                acc = __builtin_amdgcn_mfma_f32_16x16x32_bf16(a[t], bv, acc, 0, 0, 0);
            }
            const int gh = h0 + oh;
            const int gw = w0 + ow + p;
            const float noi = nb[(size_t)gh * W_ + gw] * sn;
            #pragma unroll
            for (int j = 0; j < 4; ++j) {
                float v = acc[j] + bias_j[j] + noi;
                v = (v >= 0.f) ? v : (LRELU * v);
                yb[((size_t)(g * 4 + j) * H_ + gh) * W_ + gw] = v * GAIN_;
            }
        }
    }
}

extern "C" void kernel_launch(void* const* d_in, const int* in_sizes, int n_in,
                              void* d_out, int out_size, void* d_ws, size_t ws_size,
                              hipStream_t stream)
{
    const float* w     = (const float*)d_in[0];
    const float* x     = (const float*)d_in[1];
    const float* noise = (const float*)d_in[2];
    const float* fcw   = (const float*)d_in[3];
    const float* fcb   = (const float*)d_in[4];
    const float* convw = (const float*)d_in[5];
    const float* convb = (const float*)d_in[6];
    const float* sn    = (const float*)d_in[7];

    float* out = (float*)d_out;
    float* ws_s = (float*)d_ws;                                        // 64 f32
    unsigned short* ws_afrag = (unsigned short*)((char*)d_ws + 256);   // 10240 u16

    k_setup1<<<1, 256, 0, stream>>>(w, fcw, fcb, ws_s, out);
    k_setup2<<<B_, 256, 0, stream>>>(ws_s, convw, ws_afrag);
    dim3 grid(W_ / TW, H_ / TH, B_);
    k_conv<<<grid, 256, 0, stream>>>(x, noise, convb, sn, ws_afrag, out + 2048);
}

// Round 2
// 181.295 us; speedup vs baseline: 1.1302x; 1.1302x over previous
//
#include <hip/hip_runtime.h>

#define H_ 1024
#define W_ 1024
#define B_ 4
#define CIN 16
#define COUT 16
#define TH 8
#define TW 64
#define LDS_COLS 66   // TW+2
#define LDS_ROWS 10   // TH+2

#define LRELU 0.2f
#define GAIN_ 1.4142135623730951f
#define EPS_ 1e-8f

typedef __attribute__((ext_vector_type(8))) short bf16x8;
typedef __attribute__((ext_vector_type(4))) float f32x4;

static __device__ __forceinline__ unsigned short f32_to_bf16(float f) {
    unsigned int u = __float_as_uint(f);
    unsigned int r = u + 0x7FFF + ((u >> 16) & 1);   // RNE
    return (unsigned short)(r >> 16);
}

// ---------------- setup 1: s[b,i] = w @ (fcw.T * 512^-0.5) + bias; copy w to out ----
__global__ __launch_bounds__(256) void k_setup1(
    const float* __restrict__ w, const float* __restrict__ fcw,
    const float* __restrict__ fcb, float* __restrict__ s_out,
    float* __restrict__ w_copy_out)
{
    __shared__ float part[256];
    const int tid = threadIdx.x;
    const int bi = tid >> 2;   // 0..63 -> (b,i)
    const int q  = tid & 3;
    const int b = bi >> 4, i = bi & 15;
    const float* wr = w + b * 512 + q * 128;
    const float* fr = fcw + i * 512 + q * 128;
    float acc = 0.f;
    #pragma unroll 8
    for (int k = 0; k < 128; ++k) acc += wr[k] * fr[k];
    part[tid] = acc;
    __syncthreads();
    if (tid < 64) {
        float v = part[tid*4] + part[tid*4+1] + part[tid*4+2] + part[tid*4+3];
        s_out[tid] = v * 0.04419417382415922f /* 512^-0.5 */ + fcb[tid & 15];
    }
    for (int e = tid; e < B_ * 512; e += 256) w_copy_out[e] = w[e];
}

// ---------------- setup 2: d[b,o], W_eff -> pre-swizzled bf16 A-fragments ----------
// afrag layout: [b][t=0..4][lane=0..63][j=0..7], A[o=lane&15][k=g*8+j],
// k -> (tap = 2t + (g>>1), i = (g&1)*8 + j); tap 9 zeroed.
__global__ __launch_bounds__(256) void k_setup2(
    const float* __restrict__ s_in, const float* __restrict__ convw,
    unsigned short* __restrict__ afrag)
{
    const int b = blockIdx.x;
    const int tid = threadIdx.x;
    __shared__ float s_sh[16];
    __shared__ float d_sh[16];
    __shared__ float wc_sh[COUT * CIN * 9];
    __shared__ float part[256];

    if (tid < 16) s_sh[tid] = s_in[b * 16 + tid];
    for (int e = tid; e < COUT * CIN * 9; e += 256)
        wc_sh[e] = convw[e] * (1.0f / 12.0f);   // (16*9)^-0.5
    __syncthreads();

    const int o = tid >> 4, i = tid & 15;
    const float si = s_sh[i];
    float acc = 0.f;
    #pragma unroll
    for (int tap = 0; tap < 9; ++tap) {
        float v = wc_sh[(o * 16 + i) * 9 + tap] * si;
        acc += v * v;
    }
    part[tid] = acc;
    __syncthreads();
    if (tid < 16) {
        float sum = EPS_;
        #pragma unroll
        for (int j = 0; j < 16; ++j) sum += part[tid * 16 + j];
        d_sh[tid] = rsqrtf(sum);
    }
    __syncthreads();

    for (int e = tid; e < 5 * 64 * 8; e += 256) {
        int t = e >> 9;
        int lane = (e >> 3) & 63;
        int j = e & 7;
        int oo = lane & 15, g = lane >> 4;
        int ii = (g & 1) * 8 + j;
        int tap = 2 * t + (g >> 1);
        float v = 0.f;
        if (tap < 9) v = wc_sh[(oo * 16 + ii) * 9 + tap] * s_sh[ii] * d_sh[oo];
        afrag[(size_t)b * (5 * 64 * 8) + e] = f32_to_bf16(v);
    }
}

// ---------------- main conv: per-tile implicit GEMM via mfma_f32_16x16x32_bf16 ------
// LDS layout: tile[chalf][row][col][8ch] -> pixel stride 16B, b128 writes/reads
// are contiguous 256B per quarter-wave (2-way bank alias = free).
__global__ __launch_bounds__(256) void k_conv(
    const float* __restrict__ x, const float* __restrict__ noise,
    const float* __restrict__ conv_bias, const float* __restrict__ sn_ptr,
    const unsigned short* __restrict__ afrag, float* __restrict__ y)
{
    __shared__ unsigned short tile[2][LDS_ROWS][LDS_COLS][8]; // 21120 B

    const int tid = threadIdx.x;
    const int bt = blockIdx.z;
    const int h0 = blockIdx.y * TH;
    const int w0 = blockIdx.x * TW;
    const float sn = sn_ptr[0];
    const float* xb = x + (size_t)bt * CIN * H_ * W_;

    // ---- stage x tile: register transpose, wide LDS writes ----
    if (tid < 160) {
        // interior: 4 consecutive pixels per thread (cols 1+4*cg .. 4+4*cg)
        const int row = tid >> 4;
        const int cg  = tid & 15;
        const int gh  = h0 - 1 + row;
        const bool okr = (gh >= 0) && (gh < H_);
        #pragma unroll
        for (int h = 0; h < 2; ++h) {
            float4 v[8];
            #pragma unroll
            for (int c = 0; c < 8; ++c) {
                v[c] = make_float4(0.f, 0.f, 0.f, 0.f);
                if (okr)
                    v[c] = *reinterpret_cast<const float4*>(
                        xb + ((size_t)(8 * h + c) * H_ + gh) * W_ + (w0 + 4 * cg));
            }
            #pragma unroll
            for (int px = 0; px < 4; ++px) {
                bf16x8 pk;
                pk[0] = (short)f32_to_bf16(px == 0 ? v[0].x : px == 1 ? v[0].y : px == 2 ? v[0].z : v[0].w);
                pk[1] = (short)f32_to_bf16(px == 0 ? v[1].x : px == 1 ? v[1].y : px == 2 ? v[1].z : v[1].w);
                pk[2] = (short)f32_to_bf16(px == 0 ? v[2].x : px == 1 ? v[2].y : px == 2 ? v[2].z : v[2].w);
                pk[3] = (short)f32_to_bf16(px == 0 ? v[3].x : px == 1 ? v[3].y : px == 2 ? v[3].z : v[3].w);
                pk[4] = (short)f32_to_bf16(px == 0 ? v[4].x : px == 1 ? v[4].y : px == 2 ? v[4].z : v[4].w);
                pk[5] = (short)f32_to_bf16(px == 0 ? v[5].x : px == 1 ? v[5].y : px == 2 ? v[5].z : v[5].w);
                pk[6] = (short)f32_to_bf16(px == 0 ? v[6].x : px == 1 ? v[6].y : px == 2 ? v[6].z : v[6].w);
                pk[7] = (short)f32_to_bf16(px == 0 ? v[7].x : px == 1 ? v[7].y : px == 2 ? v[7].z : v[7].w);
                *reinterpret_cast<bf16x8*>(&tile[h][row][1 + 4 * cg + px][0]) = pk;
            }
        }
    } else if (tid < 180) {
        // edge columns: col 0 (gw = w0-1) and col 65 (gw = w0+64)
        const int u    = tid - 160;
        const int row  = u >> 1;
        const int side = u & 1;
        const int col  = side * (LDS_COLS - 1);
        const int gh   = h0 - 1 + row;
        const int gw   = w0 - 1 + col;
        const bool ok  = (gh >= 0) && (gh < H_) && (gw >= 0) && (gw < W_);
        #pragma unroll
        for (int h = 0; h < 2; ++h) {
            bf16x8 pk;
            #pragma unroll
            for (int c = 0; c < 8; ++c) {
                float v = ok ? xb[((size_t)(8 * h + c) * H_ + gh) * W_ + gw] : 0.f;
                pk[c] = (short)f32_to_bf16(v);
            }
            *reinterpret_cast<bf16x8*>(&tile[h][row][col][0]) = pk;
        }
    }

    const int lane  = tid & 63;
    const int wid   = tid >> 6;
    const int p     = lane & 15;
    const int g     = lane >> 4;
    const int ghalf = g >> 1;
    const int chalf = g & 1;

    // preload A-fragments (per-batch effective weights) and bias
    bf16x8 a[5];
    {
        const bf16x8* ap =
            reinterpret_cast<const bf16x8*>(afrag + (size_t)bt * 5 * 64 * 8);
        #pragma unroll
        for (int t = 0; t < 5; ++t) a[t] = ap[t * 64 + lane];
    }
    float bias_j[4];
    #pragma unroll
    for (int j = 0; j < 4; ++j) bias_j[j] = conv_bias[g * 4 + j];

    // per-lane tap offsets for the 5 K-slices
    int lroff[5], lcoff[5];
    #pragma unroll
    for (int t = 0; t < 5; ++t) {
        int tap = 2 * t + ghalf;
        if (tap > 8) tap = 8;        // padded slot; A is zero there
        lroff[t] = tap / 3;
        lcoff[t] = tap % 3;
    }

    __syncthreads();

    float* yb = y + (size_t)bt * COUT * H_ * W_;
    const float* nb = noise + (size_t)bt * H_ * W_;

    #pragma unroll
    for (int rr = 0; rr < 2; ++rr) {
        const int oh = wid * 2 + rr;
        #pragma unroll
        for (int gc = 0; gc < 4; ++gc) {
            const int ow = gc * 16;
            f32x4 acc = {0.f, 0.f, 0.f, 0.f};
            #pragma unroll
            for (int t = 0; t < 5; ++t) {
                const bf16x8 bv = *reinterpret_cast<const bf16x8*>(
                    &tile[chalf][oh + lroff[t]][ow + p + lcoff[t]][0]);
                acc = __builtin_amdgcn_mfma_f32_16x16x32_bf16(a[t], bv, acc, 0, 0, 0);
            }
            const int gh = h0 + oh;
            const int gw = w0 + ow + p;
            const float noi = nb[(size_t)gh * W_ + gw] * sn;
            #pragma unroll
            for (int j = 0; j < 4; ++j) {
                float v = acc[j] + bias_j[j] + noi;
                v = (v >= 0.f) ? v : (LRELU * v);
                yb[((size_t)(g * 4 + j) * H_ + gh) * W_ + gw] = v * GAIN_;
            }
        }
    }
}

extern "C" void kernel_launch(void* const* d_in, const int* in_sizes, int n_in,
                              void* d_out, int out_size, void* d_ws, size_t ws_size,
                              hipStream_t stream)
{
    const float* w     = (const float*)d_in[0];
    const float* x     = (const float*)d_in[1];
    const float* noise = (const float*)d_in[2];
    const float* fcw   = (const float*)d_in[3];
    const float* fcb   = (const float*)d_in[4];
    const float* convw = (const float*)d_in[5];
    const float* convb = (const float*)d_in[6];
    const float* sn    = (const float*)d_in[7];

    float* out = (float*)d_out;
    float* ws_s = (float*)d_ws;                                        // 64 f32
    unsigned short* ws_afrag = (unsigned short*)((char*)d_ws + 256);   // 10240 u16

    k_setup1<<<1, 256, 0, stream>>>(w, fcw, fcb, ws_s, out);
    k_setup2<<<B_, 256, 0, stream>>>(ws_s, convw, ws_afrag);
    dim3 grid(W_ / TW, H_ / TH, B_);
    k_conv<<<grid, 256, 0, stream>>>(x, noise, convb, sn, ws_afrag, out + 2048);
}